// Round 6
// baseline (345.439 us; speedup 1.0000x reference)
//
#include <hip/hip_runtime.h>
#include <cstdint>
#include <cstddef>

#define BATCH 16384
#define FEAT  128
#define HID   1024

using bf16x8  = __attribute__((ext_vector_type(8))) __bf16;
using f32x4   = __attribute__((ext_vector_type(4))) float;
using ushort8 = __attribute__((ext_vector_type(8))) unsigned short;

__device__ __forceinline__ unsigned short f2bf(float f) {
  union { float f; unsigned u; } v; v.f = f;
  unsigned r = v.u + 0x7FFFu + ((v.u >> 16) & 1u);
  return (unsigned short)(r >> 16);
}
__device__ __forceinline__ float bf2f(unsigned short b) {
  union { unsigned u; float f; } v; v.u = (unsigned)b << 16;
  return v.f;
}

__device__ __forceinline__ void async16(const unsigned short* g, unsigned short* l) {
  __builtin_amdgcn_global_load_lds(
      (const __attribute__((address_space(1))) unsigned int*)g,
      (__attribute__((address_space(3))) unsigned int*)l, 16, 0, 0);
}

// ============================================================================
// gk: proven 2-phase double-buffered GEMM (exact R0 structure).
// Ledger: R7 split-G2 regressed; R8 128x128 DUAL 264 regs = 1 blk/CU (bad);
// R10/11 64x128 dual MINW=4 -> 38% occ; R12 Euler FAILED log_det, RK2 final;
// R13 eval-1 tangent dead -> primal-only; R15 eval-1 retiled 128^2 (R0=309.8).
// R16-R19: 8-phase gk8 arc — NaN twice (wave-non-uniform publishes), then
//   112us@25% / 117us@24% — WORSE than 2-phase (96us@31%). Abandoned.
// R20: counted-vmcnt 3-buffer pipeline NEUTRAL per-kernel (95us@31.3%),
//   negative globally (LDS 49KB -> occ 28.8%, total 327). Reverted.
// DIAGNOSIS: dual 64x128 reads 12 ds_read_b128 per 16 MFMA (vs 8 for the
//   128^2 single) -> LDS-read-bound (~48KB/blk-iter vs ~258cyc MFMA) ->
//   31% MfmaUtil cap. Fix is structural: single-stream the big dual GEMM.
// R21: EPI 9 = M-stacked single-stream epilogue (rows<BATCH: tanh+bias,
//   else raw bf16) so G2k2 runs as the proven 128^2 single over M=32768.
//   TRM=1 = A2-staging transform for G3k2: dh2 = (1-h2^2)*D1raw computed
//   in-staging (global loads + VALU + ds_write to the async16 slot).
// ============================================================================
template <int BM, int BN, int NXB, int NBY, int DUAL, int EPI, int MINW = 1, int TRM = 0>
__global__ __launch_bounds__(256, MINW) void gk(
    const unsigned short* __restrict__ A1, const unsigned short* __restrict__ A2,
    const unsigned short* __restrict__ Bt, int K,
    const float* __restrict__ bias, const float* __restrict__ w1last, float tval,
    const unsigned short* __restrict__ epsb,
    unsigned short* __restrict__ outH,
    float* __restrict__ z0, unsigned short* __restrict__ zsb,
    float* __restrict__ ld0,
    float czs, float dt6, int finish,
    float* __restrict__ finZ, float* __restrict__ finLd)
{
  constexpr int WM = BM / 2, WN = BN / 2;
  constexpr int RT = WM / 16, CT = WN / 16;
  constexpr int ACH = BM / 16;                       // chunks per A stream
  constexpr int NCH = (DUAL ? 2 : 1) * ACH + BN / 16;
  constexpr int NCHW = (NCH + 3) / 4;                // chunk-loop trips per wave

  __shared__ __align__(16) unsigned short lds[2][NCH * 512];
  __shared__ float rsum[BM];

  const int tid = threadIdx.x;
  const int wave = tid >> 6, lane = tid & 63;
  int xb, yb;
  if constexpr (NBY > 1) {
    const int xcd = (int)blockIdx.x & 7;   // dispatch round-robin -> XCD
    const int l   = (int)blockIdx.x >> 3;  // local index within XCD
    xb = xcd * (NXB / 8) + (l / NBY);      // contiguous M-range per XCD
    yb = l % NBY;                          // sweep N-strips fastest
  } else {
    xb = ((int)blockIdx.x & 7) * (NXB / 8) + ((int)blockIdx.x >> 3);
    yb = 0;
  }
  const int m0 = xb * BM, n0 = yb * BN;
  const int wm0 = (wave >> 1) * WM, wn0 = (wave & 1) * WN;

  f32x4 acc0[RT][CT] = {};
  f32x4 acc1[DUAL ? RT : 1][DUAL ? CT : 1] = {};
  if constexpr (EPI == 3 && DUAL) { if (tid < BM) rsum[tid] = 0.f; }

  const int r = lane >> 2;
  const int q = (lane & 3) ^ ((r >> 1) & 3);
  const int gcol = q * 8;

  auto issue = [&](int k0, int b) {
    unsigned short* ldsb = &lds[b][0];
#pragma unroll
    for (int j = 0; j < NCHW; ++j) {
      const int cid = wave + 4 * j;            // wave-uniform
      if constexpr (NCH % 4 != 0) { if (cid >= NCH) continue; }
      const unsigned short* src; int row0;
      if constexpr (DUAL) {
        if (cid < ACH)            { src = A1; row0 = m0 + cid * 16; }
        else if (cid < 2 * ACH)   { src = A2; row0 = m0 + (cid - ACH) * 16; }
        else                      { src = Bt; row0 = n0 + (cid - 2 * ACH) * 16; }
      } else {
        if (cid < ACH)            { src = A1; row0 = m0 + cid * 16; }
        else                      { src = Bt; row0 = n0 + (cid - ACH) * 16; }
      }
      const size_t off = (size_t)(row0 + r) * K + k0 + gcol;
      if constexpr (TRM && DUAL) {
        // A2-range chunks: build dh2 = (1 - h2^2) * D1raw in-staging.
        // h2 lives at the SAME offset in A1 (rows match by construction);
        // those lines are L2-hot (also fetched by this block's A1 async16).
        if (cid >= ACH && cid < 2 * ACH) {
          const ushort8 dv = *(const ushort8*)(src + off);   // D1raw
          const ushort8 hv = *(const ushort8*)(A1 + off);    // h2
          ushort8 res;
#pragma unroll
          for (int e = 0; e < 8; ++e) {
            const float h = bf2f(hv[e]);
            res[e] = f2bf((1.f - h * h) * bf2f(dv[e]));
          }
          // lane-linear slot identical to async16's implicit dest
          *(ushort8*)(ldsb + cid * 512 + lane * 8) = res;
          continue;
        }
      }
      async16(src + off, ldsb + cid * 512);
    }
  };

  const int r2 = lane & 15, q2 = lane >> 4;
  const int ro = r2 * 32 + ((q2 ^ ((r2 >> 1) & 3)) * 8);
  constexpr int BOFF = (DUAL ? 2 : 1) * ACH;

  issue(0, 0);
  const int NIT = K >> 5;
  for (int it = 0; it < NIT; ++it) {
    __syncthreads();
    if (it + 1 < NIT) issue((it + 1) << 5, (it + 1) & 1);
    const unsigned short* buf = &lds[it & 1][0];

    bf16x8 af1[RT], af2[DUAL ? RT : 1], bfr[CT];
#pragma unroll
    for (int i = 0; i < RT; ++i) {
      af1[i] = *(const bf16x8*)&buf[((wave >> 1) * RT + i) * 512 + ro];
      if constexpr (DUAL)
        af2[i] = *(const bf16x8*)&buf[(ACH + (wave >> 1) * RT + i) * 512 + ro];
    }
#pragma unroll
    for (int j = 0; j < CT; ++j)
      bfr[j] = *(const bf16x8*)&buf[(BOFF + (wave & 1) * CT + j) * 512 + ro];

#pragma unroll
    for (int i = 0; i < RT; ++i)
#pragma unroll
      for (int j = 0; j < CT; ++j) {
        acc0[i][j] = __builtin_amdgcn_mfma_f32_16x16x32_bf16(af1[i], bfr[j], acc0[i][j], 0, 0, 0);
        if constexpr (DUAL)
          acc1[i][j] = __builtin_amdgcn_mfma_f32_16x16x32_bf16(af2[i], bfr[j], acc1[i][j], 0, 0, 0);
      }
  }

  if constexpr (EPI == 2) {
#pragma unroll
    for (int i = 0; i < RT; ++i)
#pragma unroll
      for (int j = 0; j < CT; ++j)
#pragma unroll
        for (int rr = 0; rr < 4; ++rr) {
          const int m = m0 + wm0 + i * 16 + ((lane >> 4) << 2) + rr;
          const int n = n0 + wn0 + j * 16 + (lane & 15);
          const size_t idx = (size_t)m * HID + n;
          float a = acc0[i][j][rr] + bias[n];
          if (w1last) a += tval * w1last[n];
          const float h = tanhf(a);
          outH[idx] = f2bf(h);
          outH[idx + (size_t)BATCH * HID] = f2bf((1.f - h * h) * acc1[i][j][rr]);
        }
  } else if constexpr (EPI == 8) {
#pragma unroll
    for (int i = 0; i < RT; ++i)
#pragma unroll
      for (int j = 0; j < CT; ++j)
#pragma unroll
        for (int rr = 0; rr < 4; ++rr) {
          const int m = m0 + wm0 + i * 16 + ((lane >> 4) << 2) + rr;
          const int n = n0 + wn0 + j * 16 + (lane & 15);
          outH[(size_t)m * HID + n] = f2bf(tanhf(acc0[i][j][rr] + bias[n]));
        }
  } else if constexpr (EPI == 9) {
    // M-stacked single-stream: rows < BATCH -> h = tanh(D + bias) (primal);
    // rows >= BATCH -> raw D (tangent pre-activation, bf16). Block-uniform.
#pragma unroll
    for (int i = 0; i < RT; ++i)
#pragma unroll
      for (int j = 0; j < CT; ++j)
#pragma unroll
        for (int rr = 0; rr < 4; ++rr) {
          const int m = m0 + wm0 + i * 16 + ((lane >> 4) << 2) + rr;
          const int n = n0 + wn0 + j * 16 + (lane & 15);
          const float a = acc0[i][j][rr];
          outH[(size_t)m * HID + n] =
              f2bf(m < BATCH ? tanhf(a + bias[n]) : a);
        }
  } else {  // EPI == 3
#pragma unroll
    for (int i = 0; i < RT; ++i)
#pragma unroll
      for (int rr = 0; rr < 4; ++rr) {
        const int ml = wm0 + i * 16 + ((lane >> 4) << 2) + rr;
        const int m = m0 + ml;
        float s = 0.f;
#pragma unroll
        for (int j = 0; j < CT; ++j) {
          const int n = n0 + wn0 + j * 16 + (lane & 15);
          const size_t idx = (size_t)m * FEAT + n;
          const float dzv = acc0[i][j][rr] + bias[n];
          if constexpr (DUAL) s += acc1[i][j][rr] * bf2f(epsb[idx]);
          if (!finish) {
            zsb[idx] = f2bf(z0[idx] + czs * dzv);
          } else {
            const float v = z0[idx] + dt6 * dzv;
            z0[idx] = v;
            zsb[idx] = f2bf(v);
            if (finZ) finZ[idx] = v;
          }
        }
        if constexpr (DUAL) {
          s += __shfl_xor(s, 8);
          s += __shfl_xor(s, 4);
          s += __shfl_xor(s, 2);
          s += __shfl_xor(s, 1);
          if ((lane & 15) == 0) atomicAdd(&rsum[ml], s);
        }
      }
    if constexpr (DUAL) {
      __syncthreads();
      if (tid < BM && finish) {
        const int m = m0 + tid;
        const float lv = ld0[m] + dt6 * (-rsum[tid]);
        ld0[m] = lv;
        if (finLd) finLd[m] = lv;
      }
    }
  }
}

// Fused prologue: 3 LDS-tiled weight transposes (fp32 -> bf16, N x R layout)
// + eps/z0/zsb/ld0 init. Blocks [0,320) do transpose tiles, rest do prep.
__global__ __launch_bounds__(256) void prologue_k(
    const float* __restrict__ W1, const float* __restrict__ W2,
    const float* __restrict__ W3,
    unsigned short* __restrict__ Wb1t, unsigned short* __restrict__ Wb2t,
    unsigned short* __restrict__ Wb3t,
    const float* __restrict__ x, const float* __restrict__ eps,
    float* __restrict__ z0, unsigned short* __restrict__ zs,
    unsigned short* __restrict__ epsb, float* __restrict__ ld0)
{
  __shared__ unsigned short t[64][65];
  const int b = blockIdx.x;
  if (b < 320) {
    const float* src; unsigned short* dst; int R, N, lb;
    if (b < 32)       { src = W1; dst = Wb1t; R = FEAT; N = HID;  lb = b; }
    else if (b < 288) { src = W2; dst = Wb2t; R = HID;  N = HID;  lb = b - 32; }
    else              { src = W3; dst = Wb3t; R = HID;  N = FEAT; lb = b - 288; }
    const int nt = N >> 6;
    const int bx = lb % nt, by = lb / nt;
    const int r0 = by << 6, c0 = bx << 6;
    const int tx = threadIdx.x & 63, ty = threadIdx.x >> 6;
#pragma unroll
    for (int k = 0; k < 16; ++k) {
      const int rr = ty * 16 + k;
      t[rr][tx] = f2bf(src[(size_t)(r0 + rr) * N + c0 + tx]);
    }
    __syncthreads();
#pragma unroll
    for (int k = 0; k < 16; ++k) {
      const int rr = ty * 16 + k;
      dst[(size_t)(c0 + rr) * R + r0 + tx] = t[tx][rr];
    }
  } else {
    const int i = (b - 320) * 256 + threadIdx.x;
    if (i < BATCH * FEAT) {
      const float v = x[i];
      z0[i] = v; zs[i] = f2bf(v);
      epsb[i] = f2bf(eps[i]);
    }
    if (i < BATCH) ld0[i] = 0.f;
  }
}

extern "C" void kernel_launch(void* const* d_in, const int* in_sizes, int n_in,
                              void* d_out, int out_size, void* d_ws, size_t ws_size,
                              hipStream_t stream) {
  const float* x   = (const float*)d_in[0];
  const float* eps = (const float*)d_in[1];
  const float* W1  = (const float*)d_in[2];   // (129, 1024)
  const float* b1  = (const float*)d_in[3];
  const float* W2  = (const float*)d_in[4];   // (1024, 1024)
  const float* b2  = (const float*)d_in[5];
  const float* W3  = (const float*)d_in[6];   // (1024, 128)
  const float* b3  = (const float*)d_in[7];
  (void)in_sizes; (void)n_in; (void)out_size; (void)ws_size;

  char* p = (char*)d_ws;
  auto alloc = [&](size_t bytes) -> void* {
    void* q = (void*)p;
    p += (bytes + 255) & ~(size_t)255;
    return q;
  };
  unsigned short* Wb1t = (unsigned short*)alloc((size_t)HID * FEAT * 2);   // [1024][128]
  unsigned short* Wb2t = (unsigned short*)alloc((size_t)HID * HID * 2);    // [1024][1024]
  unsigned short* Wb3t = (unsigned short*)alloc((size_t)FEAT * HID * 2);   // [128][1024]
  unsigned short* epsb = (unsigned short*)alloc((size_t)BATCH * FEAT * 2);
  unsigned short* zsb  = (unsigned short*)alloc((size_t)BATCH * FEAT * 2);
  float* z0  = (float*)alloc((size_t)BATCH * FEAT * 4);
  float* ld0 = (float*)alloc((size_t)BATCH * 4);
  unsigned short* h1d = (unsigned short*)alloc((size_t)2 * BATCH * HID * 2);
  unsigned short* h2d = (unsigned short*)alloc((size_t)2 * BATCH * HID * 2);

  const int GB = (BATCH * FEAT + 255) / 256;
  prologue_k<<<dim3(320 + GB), dim3(256), 0, stream>>>(
      W1, W2, W3, Wb1t, Wb2t, Wb3t, x, eps, z0, zsb, epsb, ld0);

  const float dt = 1.f;
  const float* w1l = W1 + (size_t)FEAT * HID;

  // ---- Midpoint RK2, single step over [0,1] ----
  // eval 1 (k1, t=0): PRIMAL ONLY.
  gk<128, 128, 128, 8, 0, 8, 4><<<dim3(1024), dim3(256), 0, stream>>>(
      zsb, nullptr, Wb1t, FEAT, b1, nullptr, 0.f, nullptr,
      h1d, nullptr, nullptr, nullptr, 0.f, 0.f, 0, nullptr, nullptr);
  // G2k1: 128^2 single-stream, K=1024.
  gk<128, 128, 128, 8, 0, 8, 4><<<dim3(1024), dim3(256), 0, stream>>>(
      h1d, nullptr, Wb2t, HID, b2, nullptr, 0.f, nullptr,
      h2d, nullptr, nullptr, nullptr, 0.f, 0.f, 0, nullptr, nullptr);
  // G3k1: dz = h2@W3+b3; zsb = bf16(z0 + dt/2*dz).
  gk<32, 64, 512, 2, 0, 3, 4><<<dim3(1024), dim3(256), 0, stream>>>(
      h2d, nullptr, Wb3t, HID, b3, nullptr, 0.f, nullptr,
      nullptr, z0, zsb, nullptr, 0.5f * dt, 0.f, 0, nullptr, nullptr);

  // eval 2 (k2, t=1/2): full primal+tangent, finish
  // G1: dual — h1 = tanh(zs@W1 + t*w1last + b1); dh1 = (1-h1^2)*(eps@W1)
  gk<64, 128, 256, 8, 1, 2, 4><<<dim3(2048), dim3(256), 0, stream>>>(
      zsb, epsb, Wb1t, FEAT, b1, w1l, 0.5f * dt, nullptr,
      h1d, nullptr, nullptr, nullptr, 0.f, 0.f, 0, nullptr, nullptr);
  // G2k2 (R21): M-stacked SINGLE-stream 128^2 over [h1; dh1] (32768x1024,
  // K=1024) — removes the dual tile's 12-reads-per-16-MFMA LDS bottleneck.
  // Rows < BATCH -> h2 = tanh(D+b2); rows >= BATCH -> raw D1 (bf16).
  gk<128, 128, 256, 8, 0, 9, 4><<<dim3(2048), dim3(256), 0, stream>>>(
      h1d, nullptr, Wb2t, HID, b2, nullptr, 0.f, nullptr,
      h2d, nullptr, nullptr, nullptr, 0.f, 0.f, 0, nullptr, nullptr);
  // G3: dual + finish — z1 = z0 + dt*dz; ld1 = dt*(-trace). TRM=1 builds
  // dh2 = (1-h2^2)*D1raw during A2 staging (h2 rows are L2-hot).
  gk<32, 128, 512, 1, 1, 3, 1, 1><<<dim3(512), dim3(256), 0, stream>>>(
      h2d, h2d + (size_t)BATCH * HID, Wb3t, HID, b3, nullptr, 0.f, epsb,
      nullptr, z0, zsb, ld0, 0.f, dt, 1,
      (float*)d_out, (float*)d_out + (size_t)BATCH * FEAT);
}

// Round 7
// 323.294 us; speedup vs baseline: 1.0685x; 1.0685x over previous
//
#include <hip/hip_runtime.h>
#include <cstdint>
#include <cstddef>

#define BATCH 16384
#define FEAT  128
#define HID   1024

using bf16x8 = __attribute__((ext_vector_type(8))) __bf16;
using f32x4  = __attribute__((ext_vector_type(4))) float;

__device__ __forceinline__ unsigned short f2bf(float f) {
  union { float f; unsigned u; } v; v.f = f;
  unsigned r = v.u + 0x7FFFu + ((v.u >> 16) & 1u);
  return (unsigned short)(r >> 16);
}
__device__ __forceinline__ float bf2f(unsigned short b) {
  union { unsigned u; float f; } v; v.u = (unsigned)b << 16;
  return v.f;
}

__device__ __forceinline__ void async16(const unsigned short* g, unsigned short* l) {
  __builtin_amdgcn_global_load_lds(
      (const __attribute__((address_space(1))) unsigned int*)g,
      (__attribute__((address_space(3))) unsigned int*)l, 16, 0, 0);
}

// ============================================================================
// gk: proven 2-phase double-buffered GEMM (exact R0 structure).
// Ledger: R7 split-G2 regressed; R8 128x128 DUAL 264 regs = 1 blk/CU (bad);
// R10/11 64x128 dual MINW=4 -> 38% occ; R12 Euler FAILED log_det, RK2 final;
// R13 eval-1 tangent dead -> primal-only; R15 eval-1 retiled 128^2 (R0=309.8).
// R16-R19: 8-phase gk8 arc — NaN twice, then 112us@25% / 117us@24%, WORSE
//   than 2-phase dual (96us@31%). Abandoned.
// R20: counted-vmcnt 3-buffer pipeline NEUTRAL per-kernel, negative global
//   (LDS 49KB -> occ 28.8%). Reverted.
// R21: M-stacked single-stream G2k2 = 598 TF < dual's 715 TF — R21's
//   "12 reads/16 MFMA" diagnosis was WRONG (dual reads 8: af1x2+af2x2+bfrx4).
//   Dual 64x128 is the best-measured shape for this geometry. Reverted.
// R22: G2k1 converted to SPLIT-DUAL — two M-streams of the same h1 matrix
//   (A2 = A1 + 1024 rows), paired WITHIN each XCD's 2048-row range
//   (m0 = (xb>>4)*2048 + (xb&15)*64) so reads/writes stay XCD-L2-local for
//   the G1k1->G2k1->G3k1 handoff chain. EPI 10 = tanh both streams, D1 at
//   +1024 rows. Same 715 TF rate as the proven dual.
// ============================================================================
template <int BM, int BN, int NXB, int NBY, int DUAL, int EPI, int MINW = 1>
__global__ __launch_bounds__(256, MINW) void gk(
    const unsigned short* __restrict__ A1, const unsigned short* __restrict__ A2,
    const unsigned short* __restrict__ Bt, int K,
    const float* __restrict__ bias, const float* __restrict__ w1last, float tval,
    const unsigned short* __restrict__ epsb,
    unsigned short* __restrict__ outH,
    float* __restrict__ z0, unsigned short* __restrict__ zsb,
    float* __restrict__ ld0,
    float czs, float dt6, int finish,
    float* __restrict__ finZ, float* __restrict__ finLd)
{
  constexpr int WM = BM / 2, WN = BN / 2;
  constexpr int RT = WM / 16, CT = WN / 16;
  constexpr int ACH = BM / 16;                       // chunks per A stream
  constexpr int NCH = (DUAL ? 2 : 1) * ACH + BN / 16;
  constexpr int NCHW = (NCH + 3) / 4;                // chunk-loop trips per wave

  __shared__ __align__(16) unsigned short lds[2][NCH * 512];
  __shared__ float rsum[BM];

  const int tid = threadIdx.x;
  const int wave = tid >> 6, lane = tid & 63;
  int xb, yb;
  if constexpr (NBY > 1) {
    const int xcd = (int)blockIdx.x & 7;   // dispatch round-robin -> XCD
    const int l   = (int)blockIdx.x >> 3;  // local index within XCD
    xb = xcd * (NXB / 8) + (l / NBY);      // contiguous M-range per XCD
    yb = l % NBY;                          // sweep N-strips fastest
  } else {
    xb = ((int)blockIdx.x & 7) * (NXB / 8) + ((int)blockIdx.x >> 3);
    yb = 0;
  }
  int m0;
  if constexpr (EPI == 10) {
    // split-dual M mapping: pair (m0, m0+1024) within each XCD's 2048-row
    // range so both streams + outputs stay XCD-L2-local. NXB must be 128.
    m0 = ((xb >> 4) << 11) + ((xb & 15) << 6);
  } else {
    m0 = xb * BM;
  }
  const int n0 = yb * BN;
  const int wm0 = (wave >> 1) * WM, wn0 = (wave & 1) * WN;

  f32x4 acc0[RT][CT] = {};
  f32x4 acc1[DUAL ? RT : 1][DUAL ? CT : 1] = {};
  if constexpr (EPI == 3 && DUAL) { if (tid < BM) rsum[tid] = 0.f; }

  const int r = lane >> 2;
  const int q = (lane & 3) ^ ((r >> 1) & 3);
  const int gcol = q * 8;

  auto issue = [&](int k0, int b) {
    unsigned short* ldsb = &lds[b][0];
#pragma unroll
    for (int j = 0; j < NCHW; ++j) {
      const int cid = wave + 4 * j;            // wave-uniform
      if constexpr (NCH % 4 != 0) { if (cid >= NCH) continue; }
      const unsigned short* src; int row0;
      if constexpr (DUAL) {
        if (cid < ACH)            { src = A1; row0 = m0 + cid * 16; }
        else if (cid < 2 * ACH)   { src = A2; row0 = m0 + (cid - ACH) * 16; }
        else                      { src = Bt; row0 = n0 + (cid - 2 * ACH) * 16; }
      } else {
        if (cid < ACH)            { src = A1; row0 = m0 + cid * 16; }
        else                      { src = Bt; row0 = n0 + (cid - ACH) * 16; }
      }
      async16(src + (size_t)(row0 + r) * K + k0 + gcol, ldsb + cid * 512);
    }
  };

  const int r2 = lane & 15, q2 = lane >> 4;
  const int ro = r2 * 32 + ((q2 ^ ((r2 >> 1) & 3)) * 8);
  constexpr int BOFF = (DUAL ? 2 : 1) * ACH;

  issue(0, 0);
  const int NIT = K >> 5;
  for (int it = 0; it < NIT; ++it) {
    __syncthreads();
    if (it + 1 < NIT) issue((it + 1) << 5, (it + 1) & 1);
    const unsigned short* buf = &lds[it & 1][0];

    bf16x8 af1[RT], af2[DUAL ? RT : 1], bfr[CT];
#pragma unroll
    for (int i = 0; i < RT; ++i) {
      af1[i] = *(const bf16x8*)&buf[((wave >> 1) * RT + i) * 512 + ro];
      if constexpr (DUAL)
        af2[i] = *(const bf16x8*)&buf[(ACH + (wave >> 1) * RT + i) * 512 + ro];
    }
#pragma unroll
    for (int j = 0; j < CT; ++j)
      bfr[j] = *(const bf16x8*)&buf[(BOFF + (wave & 1) * CT + j) * 512 + ro];

#pragma unroll
    for (int i = 0; i < RT; ++i)
#pragma unroll
      for (int j = 0; j < CT; ++j) {
        acc0[i][j] = __builtin_amdgcn_mfma_f32_16x16x32_bf16(af1[i], bfr[j], acc0[i][j], 0, 0, 0);
        if constexpr (DUAL)
          acc1[i][j] = __builtin_amdgcn_mfma_f32_16x16x32_bf16(af2[i], bfr[j], acc1[i][j], 0, 0, 0);
      }
  }

  if constexpr (EPI == 2) {
#pragma unroll
    for (int i = 0; i < RT; ++i)
#pragma unroll
      for (int j = 0; j < CT; ++j)
#pragma unroll
        for (int rr = 0; rr < 4; ++rr) {
          const int m = m0 + wm0 + i * 16 + ((lane >> 4) << 2) + rr;
          const int n = n0 + wn0 + j * 16 + (lane & 15);
          const size_t idx = (size_t)m * HID + n;
          float a = acc0[i][j][rr] + bias[n];
          if (w1last) a += tval * w1last[n];
          const float h = tanhf(a);
          outH[idx] = f2bf(h);
          outH[idx + (size_t)BATCH * HID] = f2bf((1.f - h * h) * acc1[i][j][rr]);
        }
  } else if constexpr (EPI == 8) {
#pragma unroll
    for (int i = 0; i < RT; ++i)
#pragma unroll
      for (int j = 0; j < CT; ++j)
#pragma unroll
        for (int rr = 0; rr < 4; ++rr) {
          const int m = m0 + wm0 + i * 16 + ((lane >> 4) << 2) + rr;
          const int n = n0 + wn0 + j * 16 + (lane & 15);
          outH[(size_t)m * HID + n] = f2bf(tanhf(acc0[i][j][rr] + bias[n]));
        }
  } else if constexpr (EPI == 10) {
    // split-dual single-activation epilogue: both streams get tanh+bias;
    // stream-2 output lands 1024 rows below stream-1 (XCD-local pair).
#pragma unroll
    for (int i = 0; i < RT; ++i)
#pragma unroll
      for (int j = 0; j < CT; ++j)
#pragma unroll
        for (int rr = 0; rr < 4; ++rr) {
          const int m = m0 + wm0 + i * 16 + ((lane >> 4) << 2) + rr;
          const int n = n0 + wn0 + j * 16 + (lane & 15);
          const size_t idx = (size_t)m * HID + n;
          outH[idx] = f2bf(tanhf(acc0[i][j][rr] + bias[n]));
          outH[idx + (size_t)1024 * HID] = f2bf(tanhf(acc1[i][j][rr] + bias[n]));
        }
  } else {  // EPI == 3
#pragma unroll
    for (int i = 0; i < RT; ++i)
#pragma unroll
      for (int rr = 0; rr < 4; ++rr) {
        const int ml = wm0 + i * 16 + ((lane >> 4) << 2) + rr;
        const int m = m0 + ml;
        float s = 0.f;
#pragma unroll
        for (int j = 0; j < CT; ++j) {
          const int n = n0 + wn0 + j * 16 + (lane & 15);
          const size_t idx = (size_t)m * FEAT + n;
          const float dzv = acc0[i][j][rr] + bias[n];
          if constexpr (DUAL) s += acc1[i][j][rr] * bf2f(epsb[idx]);
          if (!finish) {
            zsb[idx] = f2bf(z0[idx] + czs * dzv);
          } else {
            const float v = z0[idx] + dt6 * dzv;
            z0[idx] = v;
            zsb[idx] = f2bf(v);
            if (finZ) finZ[idx] = v;
          }
        }
        if constexpr (DUAL) {
          s += __shfl_xor(s, 8);
          s += __shfl_xor(s, 4);
          s += __shfl_xor(s, 2);
          s += __shfl_xor(s, 1);
          if ((lane & 15) == 0) atomicAdd(&rsum[ml], s);
        }
      }
    if constexpr (DUAL) {
      __syncthreads();
      if (tid < BM && finish) {
        const int m = m0 + tid;
        const float lv = ld0[m] + dt6 * (-rsum[tid]);
        ld0[m] = lv;
        if (finLd) finLd[m] = lv;
      }
    }
  }
}

// Fused prologue: 3 LDS-tiled weight transposes (fp32 -> bf16, N x R layout)
// + eps/z0/zsb/ld0 init. Blocks [0,320) do transpose tiles, rest do prep.
__global__ __launch_bounds__(256) void prologue_k(
    const float* __restrict__ W1, const float* __restrict__ W2,
    const float* __restrict__ W3,
    unsigned short* __restrict__ Wb1t, unsigned short* __restrict__ Wb2t,
    unsigned short* __restrict__ Wb3t,
    const float* __restrict__ x, const float* __restrict__ eps,
    float* __restrict__ z0, unsigned short* __restrict__ zs,
    unsigned short* __restrict__ epsb, float* __restrict__ ld0)
{
  __shared__ unsigned short t[64][65];
  const int b = blockIdx.x;
  if (b < 320) {
    const float* src; unsigned short* dst; int R, N, lb;
    if (b < 32)       { src = W1; dst = Wb1t; R = FEAT; N = HID;  lb = b; }
    else if (b < 288) { src = W2; dst = Wb2t; R = HID;  N = HID;  lb = b - 32; }
    else              { src = W3; dst = Wb3t; R = HID;  N = FEAT; lb = b - 288; }
    const int nt = N >> 6;
    const int bx = lb % nt, by = lb / nt;
    const int r0 = by << 6, c0 = bx << 6;
    const int tx = threadIdx.x & 63, ty = threadIdx.x >> 6;
#pragma unroll
    for (int k = 0; k < 16; ++k) {
      const int rr = ty * 16 + k;
      t[rr][tx] = f2bf(src[(size_t)(r0 + rr) * N + c0 + tx]);
    }
    __syncthreads();
#pragma unroll
    for (int k = 0; k < 16; ++k) {
      const int rr = ty * 16 + k;
      dst[(size_t)(c0 + rr) * R + r0 + tx] = t[tx][rr];
    }
  } else {
    const int i = (b - 320) * 256 + threadIdx.x;
    if (i < BATCH * FEAT) {
      const float v = x[i];
      z0[i] = v; zs[i] = f2bf(v);
      epsb[i] = f2bf(eps[i]);
    }
    if (i < BATCH) ld0[i] = 0.f;
  }
}

extern "C" void kernel_launch(void* const* d_in, const int* in_sizes, int n_in,
                              void* d_out, int out_size, void* d_ws, size_t ws_size,
                              hipStream_t stream) {
  const float* x   = (const float*)d_in[0];
  const float* eps = (const float*)d_in[1];
  const float* W1  = (const float*)d_in[2];   // (129, 1024)
  const float* b1  = (const float*)d_in[3];
  const float* W2  = (const float*)d_in[4];   // (1024, 1024)
  const float* b2  = (const float*)d_in[5];
  const float* W3  = (const float*)d_in[6];   // (1024, 128)
  const float* b3  = (const float*)d_in[7];
  (void)in_sizes; (void)n_in; (void)out_size; (void)ws_size;

  char* p = (char*)d_ws;
  auto alloc = [&](size_t bytes) -> void* {
    void* q = (void*)p;
    p += (bytes + 255) & ~(size_t)255;
    return q;
  };
  unsigned short* Wb1t = (unsigned short*)alloc((size_t)HID * FEAT * 2);   // [1024][128]
  unsigned short* Wb2t = (unsigned short*)alloc((size_t)HID * HID * 2);    // [1024][1024]
  unsigned short* Wb3t = (unsigned short*)alloc((size_t)FEAT * HID * 2);   // [128][1024]
  unsigned short* epsb = (unsigned short*)alloc((size_t)BATCH * FEAT * 2);
  unsigned short* zsb  = (unsigned short*)alloc((size_t)BATCH * FEAT * 2);
  float* z0  = (float*)alloc((size_t)BATCH * FEAT * 4);
  float* ld0 = (float*)alloc((size_t)BATCH * 4);
  unsigned short* h1d = (unsigned short*)alloc((size_t)2 * BATCH * HID * 2);
  unsigned short* h2d = (unsigned short*)alloc((size_t)2 * BATCH * HID * 2);

  const int GB = (BATCH * FEAT + 255) / 256;
  prologue_k<<<dim3(320 + GB), dim3(256), 0, stream>>>(
      W1, W2, W3, Wb1t, Wb2t, Wb3t, x, eps, z0, zsb, epsb, ld0);

  const float dt = 1.f;
  const float* w1l = W1 + (size_t)FEAT * HID;

  // ---- Midpoint RK2, single step over [0,1] ----
  // eval 1 (k1, t=0): PRIMAL ONLY.
  gk<128, 128, 128, 8, 0, 8, 4><<<dim3(1024), dim3(256), 0, stream>>>(
      zsb, nullptr, Wb1t, FEAT, b1, nullptr, 0.f, nullptr,
      h1d, nullptr, nullptr, nullptr, 0.f, 0.f, 0, nullptr, nullptr);
  // G2k1 (R22): SPLIT-DUAL 64x128 — streams (m0, m0+1024) within each XCD's
  // 2048-row range share B-frags (proven 715 TF shape). EPI 10 = tanh both.
  gk<64, 128, 128, 8, 1, 10, 4><<<dim3(1024), dim3(256), 0, stream>>>(
      h1d, h1d + (size_t)1024 * HID, Wb2t, HID, b2, nullptr, 0.f, nullptr,
      h2d, nullptr, nullptr, nullptr, 0.f, 0.f, 0, nullptr, nullptr);
  // G3k1: dz = h2@W3+b3; zsb = bf16(z0 + dt/2*dz).
  gk<32, 64, 512, 2, 0, 3, 4><<<dim3(1024), dim3(256), 0, stream>>>(
      h2d, nullptr, Wb3t, HID, b3, nullptr, 0.f, nullptr,
      nullptr, z0, zsb, nullptr, 0.5f * dt, 0.f, 0, nullptr, nullptr);

  // eval 2 (k2, t=1/2): full primal+tangent, finish
  // G1: dual — h1 = tanh(zs@W1 + t*w1last + b1); dh1 = (1-h1^2)*(eps@W1)
  gk<64, 128, 256, 8, 1, 2, 4><<<dim3(2048), dim3(256), 0, stream>>>(
      zsb, epsb, Wb1t, FEAT, b1, w1l, 0.5f * dt, nullptr,
      h1d, nullptr, nullptr, nullptr, 0.f, 0.f, 0, nullptr, nullptr);
  // G2k2: dual 64x128 (proven 715 TF).
  gk<64, 128, 256, 8, 1, 2, 4><<<dim3(2048), dim3(256), 0, stream>>>(
      h1d, h1d + (size_t)BATCH * HID, Wb2t, HID, b2, nullptr, 0.f, nullptr,
      h2d, nullptr, nullptr, nullptr, 0.f, 0.f, 0, nullptr, nullptr);
  // G3: dual + finish — z1 = z0 + dt*dz; ld1 = dt*(-trace)
  gk<32, 128, 512, 1, 1, 3><<<dim3(512), dim3(256), 0, stream>>>(
      h2d, h2d + (size_t)BATCH * HID, Wb3t, HID, b3, nullptr, 0.f, epsb,
      nullptr, z0, zsb, ld0, 0.f, dt, 1,
      (float*)d_out, (float*)d_out + (size_t)BATCH * FEAT);
}

// Round 8
// 318.440 us; speedup vs baseline: 1.0848x; 1.0152x over previous
//
#include <hip/hip_runtime.h>
#include <cstdint>
#include <cstddef>

#define BATCH 16384
#define FEAT  128
#define HID   1024

using bf16x8 = __attribute__((ext_vector_type(8))) __bf16;
using f32x4  = __attribute__((ext_vector_type(4))) float;

__device__ __forceinline__ unsigned short f2bf(float f) {
  union { float f; unsigned u; } v; v.f = f;
  unsigned r = v.u + 0x7FFFu + ((v.u >> 16) & 1u);
  return (unsigned short)(r >> 16);
}
__device__ __forceinline__ float bf2f(unsigned short b) {
  union { unsigned u; float f; } v; v.u = (unsigned)b << 16;
  return v.f;
}

__device__ __forceinline__ void async16(const unsigned short* g, unsigned short* l) {
  __builtin_amdgcn_global_load_lds(
      (const __attribute__((address_space(1))) unsigned int*)g,
      (__attribute__((address_space(3))) unsigned int*)l, 16, 0, 0);
}

// ============================================================================
// gk: proven 2-phase double-buffered GEMM (exact R0 structure).
// Ledger: R7 split-G2 regressed; R8 128x128 DUAL 264 regs = 1 blk/CU (bad);
// R10/11 64x128 dual MINW=4 -> 38% occ; R12 Euler FAILED log_det, RK2 final;
// R13 eval-1 tangent dead -> primal-only; R15 eval-1 retiled 128^2 (R0=309.8).
// R16-R19: 8-phase gk8 arc — NaN twice, then 112us@25% / 117us@24%, WORSE
//   than 2-phase (96us@31%). Abandoned.
// R20: counted-vmcnt 3-buffer pipeline NEUTRAL per-kernel, negative global
//   (LDS 49KB -> occ 28.8%). Reverted.
// R21: M-stacked single-stream G2k2 (grid 2048) = 598 TF < dual's 715.
// R22: split-dual G2k1 (grid 1024) = 484 TF < single's 598. Together with
//   R21: dual-64x128 and single-128^2 have IDENTICAL read:MFMA ratios
//   (8:16; WM*WN/(WM+WN)=32 both) — G2k2's 715 TF is dispatch-specific
//   (L2-warm operands from G1k2), not shape-intrinsic. Do not re-try shapes.
// R23: exact R0 GEMM config restored; dead-traffic elimination only:
//   z0 buffer removed (was pure x-copy -> read x), ld0 removed (was 0),
//   finish-path z0/zsb writes dropped (nothing runs after G3k2),
//   b1+0.5*w1last pre-folded into b1mid (prologue).
// ============================================================================
template <int BM, int BN, int NXB, int NBY, int DUAL, int EPI, int MINW = 1>
__global__ __launch_bounds__(256, MINW) void gk(
    const unsigned short* __restrict__ A1, const unsigned short* __restrict__ A2,
    const unsigned short* __restrict__ Bt, int K,
    const float* __restrict__ bias, const float* __restrict__ w1last, float tval,
    const unsigned short* __restrict__ epsb,
    unsigned short* __restrict__ outH,
    const float* __restrict__ xin, unsigned short* __restrict__ zsb,
    float czs, float dt6, int finish,
    float* __restrict__ finZ, float* __restrict__ finLd)
{
  constexpr int WM = BM / 2, WN = BN / 2;
  constexpr int RT = WM / 16, CT = WN / 16;
  constexpr int ACH = BM / 16;                       // chunks per A stream
  constexpr int NCH = (DUAL ? 2 : 1) * ACH + BN / 16;
  constexpr int NCHW = (NCH + 3) / 4;                // chunk-loop trips per wave

  __shared__ __align__(16) unsigned short lds[2][NCH * 512];
  __shared__ float rsum[BM];

  const int tid = threadIdx.x;
  const int wave = tid >> 6, lane = tid & 63;
  int xb, yb;
  if constexpr (NBY > 1) {
    const int xcd = (int)blockIdx.x & 7;   // dispatch round-robin -> XCD
    const int l   = (int)blockIdx.x >> 3;  // local index within XCD
    xb = xcd * (NXB / 8) + (l / NBY);      // contiguous M-range per XCD
    yb = l % NBY;                          // sweep N-strips fastest
  } else {
    xb = ((int)blockIdx.x & 7) * (NXB / 8) + ((int)blockIdx.x >> 3);
    yb = 0;
  }
  const int m0 = xb * BM, n0 = yb * BN;
  const int wm0 = (wave >> 1) * WM, wn0 = (wave & 1) * WN;

  f32x4 acc0[RT][CT] = {};
  f32x4 acc1[DUAL ? RT : 1][DUAL ? CT : 1] = {};
  if constexpr (EPI == 3 && DUAL) { if (tid < BM) rsum[tid] = 0.f; }

  const int r = lane >> 2;
  const int q = (lane & 3) ^ ((r >> 1) & 3);
  const int gcol = q * 8;

  auto issue = [&](int k0, int b) {
    unsigned short* ldsb = &lds[b][0];
#pragma unroll
    for (int j = 0; j < NCHW; ++j) {
      const int cid = wave + 4 * j;            // wave-uniform
      if constexpr (NCH % 4 != 0) { if (cid >= NCH) continue; }
      const unsigned short* src; int row0;
      if constexpr (DUAL) {
        if (cid < ACH)            { src = A1; row0 = m0 + cid * 16; }
        else if (cid < 2 * ACH)   { src = A2; row0 = m0 + (cid - ACH) * 16; }
        else                      { src = Bt; row0 = n0 + (cid - 2 * ACH) * 16; }
      } else {
        if (cid < ACH)            { src = A1; row0 = m0 + cid * 16; }
        else                      { src = Bt; row0 = n0 + (cid - ACH) * 16; }
      }
      async16(src + (size_t)(row0 + r) * K + k0 + gcol, ldsb + cid * 512);
    }
  };

  const int r2 = lane & 15, q2 = lane >> 4;
  const int ro = r2 * 32 + ((q2 ^ ((r2 >> 1) & 3)) * 8);
  constexpr int BOFF = (DUAL ? 2 : 1) * ACH;

  issue(0, 0);
  const int NIT = K >> 5;
  for (int it = 0; it < NIT; ++it) {
    __syncthreads();
    if (it + 1 < NIT) issue((it + 1) << 5, (it + 1) & 1);
    const unsigned short* buf = &lds[it & 1][0];

    bf16x8 af1[RT], af2[DUAL ? RT : 1], bfr[CT];
#pragma unroll
    for (int i = 0; i < RT; ++i) {
      af1[i] = *(const bf16x8*)&buf[((wave >> 1) * RT + i) * 512 + ro];
      if constexpr (DUAL)
        af2[i] = *(const bf16x8*)&buf[(ACH + (wave >> 1) * RT + i) * 512 + ro];
    }
#pragma unroll
    for (int j = 0; j < CT; ++j)
      bfr[j] = *(const bf16x8*)&buf[(BOFF + (wave & 1) * CT + j) * 512 + ro];

#pragma unroll
    for (int i = 0; i < RT; ++i)
#pragma unroll
      for (int j = 0; j < CT; ++j) {
        acc0[i][j] = __builtin_amdgcn_mfma_f32_16x16x32_bf16(af1[i], bfr[j], acc0[i][j], 0, 0, 0);
        if constexpr (DUAL)
          acc1[i][j] = __builtin_amdgcn_mfma_f32_16x16x32_bf16(af2[i], bfr[j], acc1[i][j], 0, 0, 0);
      }
  }

  if constexpr (EPI == 2) {
#pragma unroll
    for (int i = 0; i < RT; ++i)
#pragma unroll
      for (int j = 0; j < CT; ++j)
#pragma unroll
        for (int rr = 0; rr < 4; ++rr) {
          const int m = m0 + wm0 + i * 16 + ((lane >> 4) << 2) + rr;
          const int n = n0 + wn0 + j * 16 + (lane & 15);
          const size_t idx = (size_t)m * HID + n;
          float a = acc0[i][j][rr] + bias[n];
          if (w1last) a += tval * w1last[n];
          const float h = tanhf(a);
          outH[idx] = f2bf(h);
          outH[idx + (size_t)BATCH * HID] = f2bf((1.f - h * h) * acc1[i][j][rr]);
        }
  } else if constexpr (EPI == 8) {
#pragma unroll
    for (int i = 0; i < RT; ++i)
#pragma unroll
      for (int j = 0; j < CT; ++j)
#pragma unroll
        for (int rr = 0; rr < 4; ++rr) {
          const int m = m0 + wm0 + i * 16 + ((lane >> 4) << 2) + rr;
          const int n = n0 + wn0 + j * 16 + (lane & 15);
          outH[(size_t)m * HID + n] = f2bf(tanhf(acc0[i][j][rr] + bias[n]));
        }
  } else {  // EPI == 3
#pragma unroll
    for (int i = 0; i < RT; ++i)
#pragma unroll
      for (int rr = 0; rr < 4; ++rr) {
        const int ml = wm0 + i * 16 + ((lane >> 4) << 2) + rr;
        const int m = m0 + ml;
        float s = 0.f;
#pragma unroll
        for (int j = 0; j < CT; ++j) {
          const int n = n0 + wn0 + j * 16 + (lane & 15);
          const size_t idx = (size_t)m * FEAT + n;
          const float dzv = acc0[i][j][rr] + bias[n];
          if constexpr (DUAL) s += acc1[i][j][rr] * bf2f(epsb[idx]);
          if (!finish) {
            // midpoint state for eval 2 (consumed by G1k2)
            zsb[idx] = f2bf(xin[idx] + czs * dzv);
          } else {
            // final: only the output buffer needs the value (nothing runs
            // after G3k2) — z0/zsb writes eliminated (R23).
            finZ[idx] = xin[idx] + dt6 * dzv;
          }
        }
        if constexpr (DUAL) {
          s += __shfl_xor(s, 8);
          s += __shfl_xor(s, 4);
          s += __shfl_xor(s, 2);
          s += __shfl_xor(s, 1);
          if ((lane & 15) == 0) atomicAdd(&rsum[ml], s);
        }
      }
    if constexpr (DUAL) {
      __syncthreads();
      if (tid < BM && finish) {
        // ld0 was zero-initialized and read once — folded away (R23).
        finLd[m0 + tid] = dt6 * (-rsum[tid]);
      }
    }
  }
}

// Fused prologue: 3 LDS-tiled weight transposes (fp32 -> bf16, N x R layout)
// + eps/zsb init + b1mid = b1 + 0.5*w1last fold (R23).
// Blocks [0,320) do transpose tiles, rest do prep.
__global__ __launch_bounds__(256) void prologue_k(
    const float* __restrict__ W1, const float* __restrict__ W2,
    const float* __restrict__ W3,
    unsigned short* __restrict__ Wb1t, unsigned short* __restrict__ Wb2t,
    unsigned short* __restrict__ Wb3t,
    const float* __restrict__ x, const float* __restrict__ eps,
    unsigned short* __restrict__ zs, unsigned short* __restrict__ epsb,
    const float* __restrict__ b1, const float* __restrict__ w1l,
    float* __restrict__ b1mid)
{
  __shared__ unsigned short t[64][65];
  const int b = blockIdx.x;
  if (b < 320) {
    const float* src; unsigned short* dst; int R, N, lb;
    if (b < 32)       { src = W1; dst = Wb1t; R = FEAT; N = HID;  lb = b; }
    else if (b < 288) { src = W2; dst = Wb2t; R = HID;  N = HID;  lb = b - 32; }
    else              { src = W3; dst = Wb3t; R = HID;  N = FEAT; lb = b - 288; }
    const int nt = N >> 6;
    const int bx = lb % nt, by = lb / nt;
    const int r0 = by << 6, c0 = bx << 6;
    const int tx = threadIdx.x & 63, ty = threadIdx.x >> 6;
#pragma unroll
    for (int k = 0; k < 16; ++k) {
      const int rr = ty * 16 + k;
      t[rr][tx] = f2bf(src[(size_t)(r0 + rr) * N + c0 + tx]);
    }
    __syncthreads();
#pragma unroll
    for (int k = 0; k < 16; ++k) {
      const int rr = ty * 16 + k;
      dst[(size_t)(c0 + rr) * R + r0 + tx] = t[tx][rr];
    }
  } else {
    const int i = (b - 320) * 256 + threadIdx.x;
    if (i < BATCH * FEAT) {
      zs[i] = f2bf(x[i]);
      epsb[i] = f2bf(eps[i]);
    }
    if (i < HID) b1mid[i] = b1[i] + 0.5f * w1l[i];
  }
}

extern "C" void kernel_launch(void* const* d_in, const int* in_sizes, int n_in,
                              void* d_out, int out_size, void* d_ws, size_t ws_size,
                              hipStream_t stream) {
  const float* x   = (const float*)d_in[0];
  const float* eps = (const float*)d_in[1];
  const float* W1  = (const float*)d_in[2];   // (129, 1024)
  const float* b1  = (const float*)d_in[3];
  const float* W2  = (const float*)d_in[4];   // (1024, 1024)
  const float* b2  = (const float*)d_in[5];
  const float* W3  = (const float*)d_in[6];   // (1024, 128)
  const float* b3  = (const float*)d_in[7];
  (void)in_sizes; (void)n_in; (void)out_size; (void)ws_size;

  char* p = (char*)d_ws;
  auto alloc = [&](size_t bytes) -> void* {
    void* q = (void*)p;
    p += (bytes + 255) & ~(size_t)255;
    return q;
  };
  unsigned short* Wb1t = (unsigned short*)alloc((size_t)HID * FEAT * 2);   // [1024][128]
  unsigned short* Wb2t = (unsigned short*)alloc((size_t)HID * HID * 2);    // [1024][1024]
  unsigned short* Wb3t = (unsigned short*)alloc((size_t)FEAT * HID * 2);   // [128][1024]
  unsigned short* epsb = (unsigned short*)alloc((size_t)BATCH * FEAT * 2);
  unsigned short* zsb  = (unsigned short*)alloc((size_t)BATCH * FEAT * 2);
  float* b1mid = (float*)alloc((size_t)HID * 4);
  unsigned short* h1d = (unsigned short*)alloc((size_t)2 * BATCH * HID * 2);
  unsigned short* h2d = (unsigned short*)alloc((size_t)2 * BATCH * HID * 2);

  const float dt = 1.f;
  const float* w1l = W1 + (size_t)FEAT * HID;

  const int GB = (BATCH * FEAT + 255) / 256;
  prologue_k<<<dim3(320 + GB), dim3(256), 0, stream>>>(
      W1, W2, W3, Wb1t, Wb2t, Wb3t, x, eps, zsb, epsb, b1, w1l, b1mid);

  // ---- Midpoint RK2, single step over [0,1] ----
  // eval 1 (k1, t=0): PRIMAL ONLY.
  gk<128, 128, 128, 8, 0, 8, 4><<<dim3(1024), dim3(256), 0, stream>>>(
      zsb, nullptr, Wb1t, FEAT, b1, nullptr, 0.f, nullptr,
      h1d, nullptr, nullptr, 0.f, 0.f, 0, nullptr, nullptr);
  // G2k1: 128^2 single-stream, K=1024 (R0 config — best measured).
  gk<128, 128, 128, 8, 0, 8, 4><<<dim3(1024), dim3(256), 0, stream>>>(
      h1d, nullptr, Wb2t, HID, b2, nullptr, 0.f, nullptr,
      h2d, nullptr, nullptr, 0.f, 0.f, 0, nullptr, nullptr);
  // G3k1: dz = h2@W3+b3; zsb = bf16(x + dt/2*dz).
  gk<32, 64, 512, 2, 0, 3, 4><<<dim3(1024), dim3(256), 0, stream>>>(
      h2d, nullptr, Wb3t, HID, b3, nullptr, 0.f, nullptr,
      nullptr, x, zsb, 0.5f * dt, 0.f, 0, nullptr, nullptr);

  // eval 2 (k2, t=1/2): full primal+tangent, finish
  // G1: dual — h1 = tanh(zs@W1 + b1mid); dh1 = (1-h1^2)*(eps@W1)
  gk<64, 128, 256, 8, 1, 2, 4><<<dim3(2048), dim3(256), 0, stream>>>(
      zsb, epsb, Wb1t, FEAT, b1mid, nullptr, 0.f, nullptr,
      h1d, nullptr, nullptr, 0.f, 0.f, 0, nullptr, nullptr);
  // G2k2: dual 64x128 (best measured for this dispatch: ~96us).
  gk<64, 128, 256, 8, 1, 2, 4><<<dim3(2048), dim3(256), 0, stream>>>(
      h1d, h1d + (size_t)BATCH * HID, Wb2t, HID, b2, nullptr, 0.f, nullptr,
      h2d, nullptr, nullptr, 0.f, 0.f, 0, nullptr, nullptr);
  // G3: dual + finish — finZ = x + dt*dz; finLd = dt*(-trace).
  gk<32, 128, 512, 1, 1, 3><<<dim3(512), dim3(256), 0, stream>>>(
      h2d, h2d + (size_t)BATCH * HID, Wb3t, HID, b3, nullptr, 0.f, epsb,
      nullptr, x, zsb, 0.f, dt, 1,
      (float*)d_out, (float*)d_out + (size_t)BATCH * FEAT);
}